// Round 5
// baseline (75.316 us; speedup 1.0000x reference)
//
#include <hip/hip_runtime.h>

// Problem constants: B=8, H=320, W=1024, CH=CW=3, MAXINS=200
#define BATCH   8
#define HW      (320 * 1024)        // 327680 pixels per batch
#define ELEMS   (HW * 9)            // 2949120 floats per batch (div by 8)
#define MAXINS  200
#define BINS    (MAXINS * 9)        // 1800 bins per batch
#define NXBLK   128                 // compress x-blocks per batch
#define SCALE      2097152.0f       // 2^21 fixed-point scale
#define INV_SCALE  (1.1f / 2097152.0f)  // fold reference's 1.1 into unscale

typedef float f32x4 __attribute__((ext_vector_type(4)));  // native vec for nt-store

// Decode an 8-element group starting at e: the 8 elements span at most 2
// pixels (8 < 9). 2 id loads + 2 divs per 8 elements.
__device__ __forceinline__ void decode8(int e, int& pix0, int& pix1,
                                        int& j0, int& b) {
    pix0 = e / 9;             // compiler magic-mul
    j0   = e - pix0 * 9;
    b    = 9 - j0;            // elements belonging to pix0 (1..9, clamped by 8)
    pix1 = (e + 7) / 9;       // == pix0 when b >= 8
}

// ---------------------------------------------------------------------------
// Compress: per-block LDS histogram in fixed-point int32 (native ds_add;
// float LDS atomicAdd CAS-expands and was the 130us wall). Partials are
// plain-stored to d_ws; a tiny reduce kernel sums them.
// ---------------------------------------------------------------------------
__global__ __launch_bounds__(256) void epp_compress(
    const int* __restrict__ inst, const float* __restrict__ src,
    int* __restrict__ part)
{
    __shared__ int bins[BINS];
    const int b = blockIdx.y;

    for (int i = threadIdx.x; i < BINS; i += 256) bins[i] = 0;
    __syncthreads();

    const int total8 = ELEMS / 8;                    // 368640 groups/batch
    const int* __restrict__ instb = inst + b * HW;
    const float4* __restrict__ srcb = (const float4*)(src + (size_t)b * ELEMS);
    const int stride = NXBLK * 256;

    for (int g = blockIdx.x * 256 + threadIdx.x; g < total8; g += stride) {
        float4 v0 = srcb[2 * g];
        float4 v1 = srcb[2 * g + 1];
        const int e = g * 8;
        int pix0, pix1, j0, cnt;
        decode8(e, pix0, pix1, j0, cnt);
        const int id0 = instb[pix0] * 9 + j0;        // LDS base for pix0 run
        const int id1 = instb[pix1] * 9 + j0 - 9;    // LDS base for pix1 run
        float vals[8] = {v0.x, v0.y, v0.z, v0.w, v1.x, v1.y, v1.z, v1.w};
#pragma unroll
        for (int k = 0; k < 8; ++k) {
            int base = (k < cnt) ? id0 : id1;
            int q = __float2int_rn(vals[k] * SCALE);
            atomicAdd(&bins[base + k], q);           // ds_add_u32 (native)
        }
    }
    __syncthreads();

    int* __restrict__ pb = part + ((size_t)b * NXBLK + blockIdx.x) * BINS;
    for (int i = threadIdx.x; i < BINS; i += 256) pb[i] = bins[i];
}

// ---------------------------------------------------------------------------
// Reduce: comp[b][i] = 1.1 * (sum of int partials) / SCALE. int64 exact.
// ---------------------------------------------------------------------------
__global__ __launch_bounds__(256) void epp_reduce(
    const int* __restrict__ part, float* __restrict__ comp)
{
    int o = blockIdx.x * 256 + threadIdx.x;
    if (o >= BATCH * BINS) return;
    int b = o / BINS, i = o - b * BINS;
    const int* __restrict__ pb = part + (size_t)b * NXBLK * BINS + i;
    long long s0 = 0, s1 = 0, s2 = 0, s3 = 0;
#pragma unroll 4
    for (int g = 0; g < NXBLK; g += 4) {
        s0 += pb[(size_t)(g + 0) * BINS];
        s1 += pb[(size_t)(g + 1) * BINS];
        s2 += pb[(size_t)(g + 2) * BINS];
        s3 += pb[(size_t)(g + 3) * BINS];
    }
    long long s = (s0 + s1) + (s2 + s3);
    comp[o] = (float)((double)s * (double)INV_SCALE);
}

// ---------------------------------------------------------------------------
// Inflate: stage per-batch table in LDS, gather, NONTEMPORAL float4 stores
// (out is write-once; nt keeps 94MB of store data from evicting the L3-
// resident src/inst that keeps compress's FETCH at 52MB).
// ---------------------------------------------------------------------------
__global__ __launch_bounds__(256) void epp_inflate(
    const int* __restrict__ inst, const float* __restrict__ comp,
    float* __restrict__ out)
{
    __shared__ float bins[BINS];
    const int b = blockIdx.y;
    const float* __restrict__ compb = comp + b * BINS;
    for (int i = threadIdx.x; i < BINS; i += 256) bins[i] = compb[i];
    __syncthreads();

    const int total8 = ELEMS / 8;
    const int* __restrict__ instb = inst + b * HW;
    f32x4* __restrict__ outb = (f32x4*)(out + (size_t)b * ELEMS);
    const int stride = gridDim.x * 256;

    for (int g = blockIdx.x * 256 + threadIdx.x; g < total8; g += stride) {
        const int e = g * 8;
        int pix0, pix1, j0, cnt;
        decode8(e, pix0, pix1, j0, cnt);
        const int id0 = instb[pix0] * 9 + j0;
        const int id1 = instb[pix1] * 9 + j0 - 9;
        float vals[8];
#pragma unroll
        for (int k = 0; k < 8; ++k) {
            int base = (k < cnt) ? id0 : id1;
            vals[k] = bins[base + k];
        }
        f32x4 w0 = {vals[0], vals[1], vals[2], vals[3]};
        f32x4 w1 = {vals[4], vals[5], vals[6], vals[7]};
        __builtin_nontemporal_store(w0, &outb[2 * g]);
        __builtin_nontemporal_store(w1, &outb[2 * g + 1]);
    }
}

// Fallback (tiny d_ws): float path with global-atomic flush (R1, correct).
__global__ __launch_bounds__(256) void epp_compress_atomic(
    const int* __restrict__ inst, const float* __restrict__ src,
    float* __restrict__ comp)
{
    __shared__ float bins[BINS];
    const int b = blockIdx.y;
    for (int i = threadIdx.x; i < BINS; i += 256) bins[i] = 0.0f;
    __syncthreads();
    const int total4 = ELEMS / 4;
    const int* __restrict__ instb = inst + b * HW;
    const float4* __restrict__ srcb = (const float4*)(src + (size_t)b * ELEMS);
    const int stride = gridDim.x * 256;
    for (int e4 = blockIdx.x * 256 + threadIdx.x; e4 < total4; e4 += stride) {
        float4 v = srcb[e4];
        const int e = e4 * 4;
        float vals[4] = {v.x, v.y, v.z, v.w};
#pragma unroll
        for (int k = 0; k < 4; ++k) {
            int ee = e + k, pix = ee / 9, j = ee - pix * 9;
            atomicAdd(&bins[instb[pix] * 9 + j], vals[k] * 1.1f);
        }
    }
    __syncthreads();
    float* __restrict__ compb = comp + b * BINS;
    for (int i = threadIdx.x; i < BINS; i += 256) atomicAdd(&compb[i], bins[i]);
}

extern "C" void kernel_launch(void* const* d_in, const int* in_sizes, int n_in,
                              void* d_out, int out_size, void* d_ws, size_t ws_size,
                              hipStream_t stream) {
    const int*   inst = (const int*)d_in[0];    // [B,1,H,W] int32
    const float* src  = (const float*)d_in[1];  // [B,H,W,3,3] f32
    float* out = (float*)d_out;                 // [B,H,W,3,3] f32

    const size_t compBytes = (size_t)BATCH * BINS * sizeof(float);       // 57.6 KB
    const size_t partBytes = (size_t)BATCH * NXBLK * BINS * sizeof(int); // 7.37 MB

    if (ws_size >= partBytes + compBytes) {
        int*   part = (int*)d_ws;
        float* comp = (float*)(part + (size_t)BATCH * NXBLK * BINS);

        dim3 cgrid(NXBLK, BATCH);                   // 1024 blocks, 16 waves/CU
        epp_compress<<<cgrid, 256, 0, stream>>>(inst, src, part);

        int rblocks = (BATCH * BINS + 255) / 256;   // 57
        epp_reduce<<<rblocks, 256, 0, stream>>>(part, comp);

        dim3 igrid(512, BATCH);                     // 4096 blocks
        epp_inflate<<<igrid, 256, 0, stream>>>(inst, comp, out);
    } else {
        float* comp = (float*)d_ws;
        (void)hipMemsetAsync(comp, 0, compBytes, stream);
        dim3 cgrid(128, BATCH);
        epp_compress_atomic<<<cgrid, 256, 0, stream>>>(inst, src, comp);
        dim3 igrid(512, BATCH);
        epp_inflate<<<igrid, 256, 0, stream>>>(inst, comp, out);
    }
}

// Round 6
// 56.468 us; speedup vs baseline: 1.3338x; 1.3338x over previous
//
#include <hip/hip_runtime.h>

// Problem constants: B=8, H=320, W=1024, CH=CW=3, MAXINS=200
#define BATCH   8
#define HW      (320 * 1024)        // 327680 pixels per batch
#define ELEMS   (HW * 9)            // 2949120 floats per batch (div by 8)
#define MAXINS  200
#define BINS    (MAXINS * 9)        // 1800 bins per batch
#define NXBLK   256                 // compress x-blocks per batch (2048 blocks = 8/CU = full occupancy)
#define SCALE      2097152.0f       // 2^21 fixed-point scale
#define INV_SCALE  (1.1f / 2097152.0f)  // fold reference's 1.1 into unscale

// Decode an 8-element group starting at e: the 8 elements span at most 2
// pixels (8 < 9). 2 id loads + 2 divs per 8 elements.
__device__ __forceinline__ void decode8(int e, int& pix0, int& pix1,
                                        int& j0, int& b) {
    pix0 = e / 9;             // compiler magic-mul
    j0   = e - pix0 * 9;
    b    = 9 - j0;            // elements belonging to pix0
    pix1 = (e + 7) / 9;       // == pix0 when b >= 8
}

// ---------------------------------------------------------------------------
// Compress: per-block LDS histogram in fixed-point int32 (native ds_add;
// float LDS atomicAdd CAS-expands and was the 130us wall). Partials are
// plain-stored to d_ws; a tiny reduce kernel sums them.
// ---------------------------------------------------------------------------
__global__ __launch_bounds__(256) void epp_compress(
    const int* __restrict__ inst, const float* __restrict__ src,
    int* __restrict__ part)
{
    __shared__ int bins[BINS];
    const int b = blockIdx.y;

    for (int i = threadIdx.x; i < BINS; i += 256) bins[i] = 0;
    __syncthreads();

    const int total8 = ELEMS / 8;                    // 368640 groups/batch
    const int* __restrict__ instb = inst + b * HW;
    const float4* __restrict__ srcb = (const float4*)(src + (size_t)b * ELEMS);
    const int stride = NXBLK * 256;

    for (int g = blockIdx.x * 256 + threadIdx.x; g < total8; g += stride) {
        float4 v0 = srcb[2 * g];
        float4 v1 = srcb[2 * g + 1];
        const int e = g * 8;
        int pix0, pix1, j0, cnt;
        decode8(e, pix0, pix1, j0, cnt);
        const int id0 = instb[pix0] * 9 + j0;        // LDS base for pix0 run
        const int id1 = instb[pix1] * 9 + j0 - 9;    // LDS base for pix1 run
        float vals[8] = {v0.x, v0.y, v0.z, v0.w, v1.x, v1.y, v1.z, v1.w};
#pragma unroll
        for (int k = 0; k < 8; ++k) {
            int base = (k < cnt) ? id0 : id1;
            int q = __float2int_rn(vals[k] * SCALE);
            atomicAdd(&bins[base + k], q);           // ds_add_u32 (native)
        }
    }
    __syncthreads();

    int* __restrict__ pb = part + ((size_t)b * NXBLK + blockIdx.x) * BINS;
    for (int i = threadIdx.x; i < BINS; i += 256) pb[i] = bins[i];
}

// ---------------------------------------------------------------------------
// Reduce: comp[b][i] = 1.1 * (sum of int partials) / SCALE. int64 exact.
// ---------------------------------------------------------------------------
__global__ __launch_bounds__(256) void epp_reduce(
    const int* __restrict__ part, float* __restrict__ comp)
{
    int o = blockIdx.x * 256 + threadIdx.x;
    if (o >= BATCH * BINS) return;
    int b = o / BINS, i = o - b * BINS;
    const int* __restrict__ pb = part + (size_t)b * NXBLK * BINS + i;
    long long s0 = 0, s1 = 0, s2 = 0, s3 = 0;
#pragma unroll 4
    for (int g = 0; g < NXBLK; g += 4) {
        s0 += pb[(size_t)(g + 0) * BINS];
        s1 += pb[(size_t)(g + 1) * BINS];
        s2 += pb[(size_t)(g + 2) * BINS];
        s3 += pb[(size_t)(g + 3) * BINS];
    }
    long long s = (s0 + s1) + (s2 + s3);
    comp[o] = (float)((double)s * (double)INV_SCALE);
}

// ---------------------------------------------------------------------------
// Inflate: stage per-batch table in LDS, gather, plain coalesced float4
// stores (the 7 TB/s fill kernel uses plain stores; nt regressed R5).
// ---------------------------------------------------------------------------
__global__ __launch_bounds__(256) void epp_inflate(
    const int* __restrict__ inst, const float* __restrict__ comp,
    float* __restrict__ out)
{
    __shared__ float bins[BINS];
    const int b = blockIdx.y;
    const float* __restrict__ compb = comp + b * BINS;
    for (int i = threadIdx.x; i < BINS; i += 256) bins[i] = compb[i];
    __syncthreads();

    const int total8 = ELEMS / 8;
    const int* __restrict__ instb = inst + b * HW;
    float4* __restrict__ outb = (float4*)(out + (size_t)b * ELEMS);
    const int stride = gridDim.x * 256;

    for (int g = blockIdx.x * 256 + threadIdx.x; g < total8; g += stride) {
        const int e = g * 8;
        int pix0, pix1, j0, cnt;
        decode8(e, pix0, pix1, j0, cnt);
        const int id0 = instb[pix0] * 9 + j0;
        const int id1 = instb[pix1] * 9 + j0 - 9;
        float vals[8];
#pragma unroll
        for (int k = 0; k < 8; ++k) {
            int base = (k < cnt) ? id0 : id1;
            vals[k] = bins[base + k];
        }
        outb[2 * g]     = make_float4(vals[0], vals[1], vals[2], vals[3]);
        outb[2 * g + 1] = make_float4(vals[4], vals[5], vals[6], vals[7]);
    }
}

// Fallback (tiny d_ws): float path with global-atomic flush (R1, correct).
__global__ __launch_bounds__(256) void epp_compress_atomic(
    const int* __restrict__ inst, const float* __restrict__ src,
    float* __restrict__ comp)
{
    __shared__ float bins[BINS];
    const int b = blockIdx.y;
    for (int i = threadIdx.x; i < BINS; i += 256) bins[i] = 0.0f;
    __syncthreads();
    const int total4 = ELEMS / 4;
    const int* __restrict__ instb = inst + b * HW;
    const float4* __restrict__ srcb = (const float4*)(src + (size_t)b * ELEMS);
    const int stride = gridDim.x * 256;
    for (int e4 = blockIdx.x * 256 + threadIdx.x; e4 < total4; e4 += stride) {
        float4 v = srcb[e4];
        const int e = e4 * 4;
        float vals[4] = {v.x, v.y, v.z, v.w};
#pragma unroll
        for (int k = 0; k < 4; ++k) {
            int ee = e + k, pix = ee / 9, j = ee - pix * 9;
            atomicAdd(&bins[instb[pix] * 9 + j], vals[k] * 1.1f);
        }
    }
    __syncthreads();
    float* __restrict__ compb = comp + b * BINS;
    for (int i = threadIdx.x; i < BINS; i += 256) atomicAdd(&compb[i], bins[i]);
}

extern "C" void kernel_launch(void* const* d_in, const int* in_sizes, int n_in,
                              void* d_out, int out_size, void* d_ws, size_t ws_size,
                              hipStream_t stream) {
    const int*   inst = (const int*)d_in[0];    // [B,1,H,W] int32
    const float* src  = (const float*)d_in[1];  // [B,H,W,3,3] f32
    float* out = (float*)d_out;                 // [B,H,W,3,3] f32

    const size_t compBytes = (size_t)BATCH * BINS * sizeof(float);       // 57.6 KB
    const size_t partBytes = (size_t)BATCH * NXBLK * BINS * sizeof(int); // 14.7 MB

    if (ws_size >= partBytes + compBytes) {
        int*   part = (int*)d_ws;
        float* comp = (float*)(part + (size_t)BATCH * NXBLK * BINS);

        dim3 cgrid(NXBLK, BATCH);                   // 2048 blocks, 32 waves/CU
        epp_compress<<<cgrid, 256, 0, stream>>>(inst, src, part);

        int rblocks = (BATCH * BINS + 255) / 256;   // 57
        epp_reduce<<<rblocks, 256, 0, stream>>>(part, comp);

        dim3 igrid(512, BATCH);                     // 4096 blocks
        epp_inflate<<<igrid, 256, 0, stream>>>(inst, comp, out);
    } else {
        float* comp = (float*)d_ws;
        (void)hipMemsetAsync(comp, 0, compBytes, stream);
        dim3 cgrid(128, BATCH);
        epp_compress_atomic<<<cgrid, 256, 0, stream>>>(inst, src, comp);
        dim3 igrid(512, BATCH);
        epp_inflate<<<igrid, 256, 0, stream>>>(inst, comp, out);
    }
}